// Round 6
// baseline (952.616 us; speedup 1.0000x reference)
//
#include <hip/hip_runtime.h>
#include <math.h>

// DenseCaps dynamic routing, MI355X. B=32, I=4096, O=32, 4x4 poses, 3 iters.
// R15: R14 (store transpose) was NEUTRAL -> write-amp wasn't the pass cost.
// Refit of R0-R14: fills are likely OUTSIDE the timed window; passes are
// ~35us each (just under the 43us fills, invisible in top-5) vs ~6-10us
// VALU/BW floors. Attack the structural 2/3: s_part round-trip (17MB w +
// 17MB r per pass) and 3 reduce launches REMOVED. Pass blocks atomicAdd
// 16 floats/thread into a 64KB L2-resident slab (per pass); squash becomes
// a thread-local 16-float op folded into the next pass's prologue (each
// thread owns one bo). v telescopes: pass2 logits use v_accum(=v0) +
// squash(slab1). Chain: zero -> pass0 -> pass1 -> pass2 -> squash_out.
// Atomic FP reorder ~1e-7 vs absmax 1.56e-2 (threshold ~1.8e-2): safe.

#define NB 32
#define NI 4096
#define NO 32
#define I_TILE 16
#define NCHUNK (NI / I_TILE)        // 256
#define B_TILE 8
#define NBG (NB / B_TILE)           // 4
#define SLAB (NB * NO * 16)         // 16384 floats = 64 KB
#define SOFF (NB * NO * 16)         // (fallback naming)
#define EPSF 1e-12f

#define W_OSTR 10                   // words per o-row: 8 data + 2 pad
#define W_ISTR (32 * W_OSTR)        // 320 words per i-slab
#define W_WORDS (I_TILE * W_ISTR)   // 5120 words = 20 KB
#define P_WORDS (B_TILE * I_TILE * 8) // 1024 words = 4 KB

typedef _Float16 v2h __attribute__((ext_vector_type(2)));

#if __has_builtin(__builtin_amdgcn_fdot2)
__device__ __forceinline__ float fdot2(v2h a, v2h b, float c) {
    return __builtin_amdgcn_fdot2(a, b, c, false);
}
#else
__device__ __forceinline__ float fdot2(v2h a, v2h b, float c) {
    return fmaf((float)a.x, (float)b.x, fmaf((float)a.y, (float)b.y, c));
}
#endif

#if __has_builtin(__builtin_amdgcn_cvt_pkrtz)
__device__ __forceinline__ v2h pk2h(float a, float b) {
    return __builtin_bit_cast(v2h, __builtin_amdgcn_cvt_pkrtz(a, b));
}
#else
__device__ __forceinline__ v2h pk2h(float a, float b) {
    v2h r; r.x = (_Float16)a; r.y = (_Float16)b; return r;
}
#endif

__device__ __forceinline__ v2h bch(unsigned u) {
    return __builtin_bit_cast(v2h, u);
}

__device__ __forceinline__ float dot4(const float4 a, const float4 b) {
    return fmaf(a.x, b.x, fmaf(a.y, b.y, fmaf(a.z, b.z, a.w * b.w)));
}

__device__ __forceinline__ void fma4(float4& s, const float c, const float4 t) {
    s.x = fmaf(c, t.x, s.x);
    s.y = fmaf(c, t.y, s.y);
    s.z = fmaf(c, t.z, s.z);
    s.w = fmaf(c, t.w, s.w);
}

__device__ __forceinline__ void add4(float4& s, const float4 t) {
    s.x += t.x; s.y += t.y; s.z += t.z; s.w += t.w;
}

// x + dpp_perm(x); ctrl: 0xB1=quad_perm xor1, 0x4E=quad_perm xor2,
// 0x141=row_half_mirror (xor7), 0x140=row_mirror (xor15).
template <int CTRL>
__device__ __forceinline__ float dpp_add(float x) {
    int xi = __builtin_bit_cast(int, x);
    int yi = __builtin_amdgcn_update_dpp(0, xi, CTRL, 0xf, 0xf, false);
    return x + __builtin_bit_cast(float, yi);
}

// sum over each 32-lane half (the o-group)
__device__ __forceinline__ float sum32(float x) {
    x = dpp_add<0xB1>(x);    // xor1
    x = dpp_add<0x4E>(x);    // xor2
    x = dpp_add<0x141>(x);   // xor7 (8-group done)
    x = dpp_add<0x140>(x);   // xor15 (16-row done)
#if __has_builtin(__builtin_amdgcn_permlane16_swap)
    typedef unsigned uv2 __attribute__((ext_vector_type(2)));
    const unsigned xi = __builtin_bit_cast(unsigned, x);
    uv2 r = __builtin_amdgcn_permlane16_swap(xi, xi, false, false);
    return __builtin_bit_cast(float, r.x) + __builtin_bit_cast(float, r.y);
#else
    int t = __builtin_amdgcn_ds_swizzle(__builtin_bit_cast(int, x), 0x401F);
    return x + __builtin_bit_cast(float, t);   // xor16 within 32-lane group
#endif
}

// ---------------- workspace zero kernel (256 KB: 3 slabs + v_accum) -------
__global__ __launch_bounds__(256) void caps_zero(float4* __restrict__ p) {
    const int i = (blockIdx.x * 256 + threadIdx.x) << 2;
    const float4 z = {0, 0, 0, 0};
    p[i] = z; p[i + 1] = z; p[i + 2] = z; p[i + 3] = z;
}

// ---------------- pass kernel (all-LDS f16 inner loop, atomic output) -----
// wsw word layout per (i,o): [m*4+z] = pair (W[2m][z], W[2m+1][z]).
// psw word layout per (b,i): [x*2+h] = pair (P[x][2h], P[x][2h+1]).
// Prologue: vv = squash(s_prev[bo]) (thread-local; pass2 adds v_accum).
// Epilogue: 16x atomicAdd into s_out[bo*16+k] (64KB L2-resident slab).
__global__ __launch_bounds__(256, 4) void caps_pass_a(
    const float* __restrict__ poses, const float* __restrict__ w,
    const float* __restrict__ s_prev, float* __restrict__ v_accum,
    float* __restrict__ s_out, const int pass)
{
    __shared__ unsigned wsw[W_WORDS];   // 20480 B
    __shared__ unsigned psw[P_WORDS];   //  4096 B
    const int tid    = threadIdx.x;
    const int chunk  = blockIdx.x;
    const int bgroup = blockIdx.y;
    const int ibase  = chunk * I_TILE;

    // ---- stage w: f32 -> f16 pairs, coalesced (each 32-half: 1KB run) ----
    #pragma unroll
    for (int r = 0; r < 4; ++r) {
        const int idx = r * 256 + tid;       // 0..1023 -> (o, i, m)
        const int o_l = idx >> 5;
        const int l   = idx & 31;
        const int i_l = l >> 1;
        const int m   = l & 1;
        const float* g = w + (((size_t)o_l * NI + ibase + i_l) << 4) + (m << 3);
        const float4 A = *(const float4*)g;        // row y=2m
        const float4 B = *(const float4*)(g + 4);  // row y=2m+1
        const v2h c0 = pk2h(A.x, B.x), c1 = pk2h(A.y, B.y);
        const v2h c2 = pk2h(A.z, B.z), c3 = pk2h(A.w, B.w);
        const int base = i_l * W_ISTR + o_l * W_OSTR + (m << 2);  // even
        *(uint2*)&wsw[base]     = make_uint2(__builtin_bit_cast(unsigned, c0),
                                             __builtin_bit_cast(unsigned, c1));
        *(uint2*)&wsw[base + 2] = make_uint2(__builtin_bit_cast(unsigned, c2),
                                             __builtin_bit_cast(unsigned, c3));
    }
    // ---- stage poses: f32 -> f16 pairs, coalesced (1KB run per b) ----
    #pragma unroll
    for (int r = 0; r < 2; ++r) {
        const int idx = r * 256 + tid;       // 0..511 -> (b, i, x)
        const int b_l = idx >> 6;
        const int l   = idx & 63;
        const int i_l = l >> 2;
        const int x   = l & 3;
        const float4 row = *(const float4*)(
            poses + (((size_t)(bgroup * B_TILE + b_l) * NI + ibase + i_l) << 4)
                  + (x << 2));
        const v2h c0 = pk2h(row.x, row.y), c1 = pk2h(row.z, row.w);
        *(uint2*)&psw[((b_l * I_TILE + i_l) << 3) + (x << 1)] =
            make_uint2(__builtin_bit_cast(unsigned, c0),
                       __builtin_bit_cast(unsigned, c1));
    }

    const int o    = tid & 31;
    const int bsub = tid >> 5;
    const int b    = bgroup * B_TILE + bsub;
    const int bo   = b * NO + o;

    float4 vv0 = {0,0,0,0}, vv1 = {0,0,0,0}, vv2 = {0,0,0,0}, vv3 = {0,0,0,0};
    if (pass > 0) {
        // inline squash of previous pass's slab (thread-local, L2-hot)
        const float4* sp = (const float4*)(s_prev + (bo << 4));
        const float4 a0 = sp[0], a1 = sp[1], a2 = sp[2], a3 = sp[3];
        const float n2 = dot4(a0,a0) + dot4(a1,a1) + dot4(a2,a2) + dot4(a3,a3);
        const float n  = sqrtf(n2 + EPSF);
        const float sc = (n2 / (1.0f + n2)) / n;
        vv0 = make_float4(sc*a0.x, sc*a0.y, sc*a0.z, sc*a0.w);
        vv1 = make_float4(sc*a1.x, sc*a1.y, sc*a1.z, sc*a1.w);
        vv2 = make_float4(sc*a2.x, sc*a2.y, sc*a2.z, sc*a2.w);
        vv3 = make_float4(sc*a3.x, sc*a3.y, sc*a3.z, sc*a3.w);
        if (pass == 1) {
            // persist v0 for pass 2 (chunk-0 blocks cover all bo exactly once
            // per bgroup; duplicate-free: grid.y partitions b)
            if (chunk == 0) {
                float4* vp = (float4*)(v_accum + (bo << 4));
                vp[0] = vv0; vp[1] = vv1; vp[2] = vv2; vp[3] = vv3;
            }
        } else {
            // logits telescope: vv = v0 + v1
            const float4* vp = (const float4*)(v_accum + (bo << 4));
            add4(vv0, vp[0]); add4(vv1, vp[1]);
            add4(vv2, vp[2]); add4(vv3, vp[3]);
        }
    }

    const unsigned* wrow = &wsw[o * W_OSTR];
    const unsigned* prow = &psw[(bsub * I_TILE) << 3];

    __syncthreads();

    float4 s0 = {0,0,0,0}, s1 = {0,0,0,0}, s2 = {0,0,0,0}, s3 = {0,0,0,0};

    #pragma unroll 2
    for (int i = 0; i < I_TILE; ++i) {
        // w: 4x ds_read_b64, 10-word stride -> <=2-way (free)
        const uint2 wa = *(const uint2*)&wrow[i * W_ISTR + 0];
        const uint2 wb = *(const uint2*)&wrow[i * W_ISTR + 2];
        const uint2 wc = *(const uint2*)&wrow[i * W_ISTR + 4];
        const uint2 wd = *(const uint2*)&wrow[i * W_ISTR + 6];
        // poses: 2x ds_read_b128, broadcast (conflict-free)
        const uint4 pa = *(const uint4*)&prow[(i << 3) + 0];
        const uint4 pb = *(const uint4*)&prow[(i << 3) + 4];

        const v2h p00 = bch(pa.x), p01 = bch(pa.y);   // x0: y01, y23
        const v2h p10 = bch(pa.z), p11 = bch(pa.w);   // x1
        const v2h p20 = bch(pb.x), p21 = bch(pb.y);   // x2
        const v2h p30 = bch(pb.z), p31 = bch(pb.w);   // x3
        const v2h w00 = bch(wa.x), w01 = bch(wa.y);   // m0: z0, z1
        const v2h w02 = bch(wb.x), w03 = bch(wb.y);   // m0: z2, z3
        const v2h w10 = bch(wc.x), w11 = bch(wc.y);   // m1: z0, z1
        const v2h w12 = bch(wd.x), w13 = bch(wd.y);   // m1: z2, z3

        float4 t0, t1, t2, t3;   // votes[x][z] = sum_y P[x][y] W[y][z]
        t0.x = fdot2(p00, w00, fdot2(p01, w10, 0.0f));
        t0.y = fdot2(p00, w01, fdot2(p01, w11, 0.0f));
        t0.z = fdot2(p00, w02, fdot2(p01, w12, 0.0f));
        t0.w = fdot2(p00, w03, fdot2(p01, w13, 0.0f));
        t1.x = fdot2(p10, w00, fdot2(p11, w10, 0.0f));
        t1.y = fdot2(p10, w01, fdot2(p11, w11, 0.0f));
        t1.z = fdot2(p10, w02, fdot2(p11, w12, 0.0f));
        t1.w = fdot2(p10, w03, fdot2(p11, w13, 0.0f));
        t2.x = fdot2(p20, w00, fdot2(p21, w10, 0.0f));
        t2.y = fdot2(p20, w01, fdot2(p21, w11, 0.0f));
        t2.z = fdot2(p20, w02, fdot2(p21, w12, 0.0f));
        t2.w = fdot2(p20, w03, fdot2(p21, w13, 0.0f));
        t3.x = fdot2(p30, w00, fdot2(p31, w10, 0.0f));
        t3.y = fdot2(p30, w01, fdot2(p31, w11, 0.0f));
        t3.z = fdot2(p30, w02, fdot2(p31, w12, 0.0f));
        t3.w = fdot2(p30, w03, fdot2(p31, w13, 0.0f));

        float cc;
        if (pass == 0) {
            cc = 1.0f / 32.0f;
        } else {
            // softmax over o without max-shift: |d| bounded (~<4), exp safe.
            const float d = dot4(t0,vv0) + dot4(t1,vv1)
                          + dot4(t2,vv2) + dot4(t3,vv3);
            const float e  = __expf(d);
            const float es = sum32(e);
            cc = __fdividef(e, es);
        }
        fma4(s0, cc, t0); fma4(s1, cc, t1);
        fma4(s2, cc, t2); fma4(s3, cc, t3);
    }

    // epilogue: 16 scalar atomics into the L2-resident slab (fire-and-forget)
    float* sb = s_out + (bo << 4);
    atomicAdd(sb +  0, s0.x); atomicAdd(sb +  1, s0.y);
    atomicAdd(sb +  2, s0.z); atomicAdd(sb +  3, s0.w);
    atomicAdd(sb +  4, s1.x); atomicAdd(sb +  5, s1.y);
    atomicAdd(sb +  6, s1.z); atomicAdd(sb +  7, s1.w);
    atomicAdd(sb +  8, s2.x); atomicAdd(sb +  9, s2.y);
    atomicAdd(sb + 10, s2.z); atomicAdd(sb + 11, s2.w);
    atomicAdd(sb + 12, s3.x); atomicAdd(sb + 13, s3.y);
    atomicAdd(sb + 14, s3.z); atomicAdd(sb + 15, s3.w);
}

// ---------------- final squash + output kernel ----------------------------
__global__ __launch_bounds__(256) void caps_squash_out(
    const float* __restrict__ s_buf, float* __restrict__ out)
{
    const int idx = blockIdx.x * 256 + threadIdx.x;   // bo
    if (idx >= NB * NO) return;
    const float4* sp = (const float4*)(s_buf + (idx << 4));
    const float4 s0 = sp[0], s1 = sp[1], s2 = sp[2], s3 = sp[3];
    const float n2 = dot4(s0,s0) + dot4(s1,s1) + dot4(s2,s2) + dot4(s3,s3);
    const float n  = sqrtf(n2 + EPSF);
    const float sc = (n2 / (1.0f + n2)) / n;
    float4* op = (float4*)(out + (idx << 4));
    op[0] = make_float4(sc*s0.x, sc*s0.y, sc*s0.z, sc*s0.w);
    op[1] = make_float4(sc*s1.x, sc*s1.y, sc*s1.z, sc*s1.w);
    op[2] = make_float4(sc*s2.x, sc*s2.y, sc*s2.z, sc*s2.w);
    op[3] = make_float4(sc*s3.x, sc*s3.y, sc*s3.z, sc*s3.w);
    out[NB * NO * 16 + idx] = sqrtf(n2 * sc * sc + EPSF);
}

// ---------------- fallback: proven v1-style kernels (tiny ws) -------------
#define FB_CHUNKS 32
#define FB_IPB (NI / FB_CHUNKS)

__device__ __forceinline__ float4 row_mm(const float4 p, const float4 w0,
                                         const float4 w1, const float4 w2,
                                         const float4 w3) {
    float4 r;
    r.x = fmaf(p.x, w0.x, fmaf(p.y, w1.x, fmaf(p.z, w2.x, p.w * w3.x)));
    r.y = fmaf(p.x, w0.y, fmaf(p.y, w1.y, fmaf(p.z, w2.y, p.w * w3.y)));
    r.z = fmaf(p.x, w0.z, fmaf(p.y, w1.z, fmaf(p.z, w2.z, p.w * w3.z)));
    r.w = fmaf(p.x, w0.w, fmaf(p.y, w1.w, fmaf(p.z, w2.w, p.w * w3.w)));
    return r;
}

__global__ __launch_bounds__(256) void caps_pass_fb(
    const float* __restrict__ poses, const float* __restrict__ w,
    const float* __restrict__ v_buf, float* __restrict__ s_buf, const int mode)
{
    const int tid   = threadIdx.x;
    const int b     = blockIdx.y;
    const int chunk = blockIdx.x;
    const int o     = tid & 31;
    const int g     = tid >> 5;

    float4 v0 = {0,0,0,0}, v1 = {0,0,0,0}, v2 = {0,0,0,0}, v3 = {0,0,0,0};
    if (mode != 0) {
        const float4* vp = (const float4*)(v_buf + (((b * NO) + o) << 4));
        v0 = vp[0]; v1 = vp[1]; v2 = vp[2]; v3 = vp[3];
    }
    float4 s0 = {0,0,0,0}, s1 = {0,0,0,0}, s2 = {0,0,0,0}, s3 = {0,0,0,0};
    const int ibase = chunk * FB_IPB + g;
    #pragma unroll 4
    for (int it = 0; it < FB_IPB / 8; ++it) {
        const int i = ibase + (it << 3);
        const float4* ppf = (const float4*)(poses + ((((size_t)b * NI) + i) << 4));
        const float4 p0 = ppf[0], p1 = ppf[1], p2 = ppf[2], p3 = ppf[3];
        const float4* wpf = (const float4*)(w + ((((size_t)o * NI) + i) << 4));
        const float4 w0 = wpf[0], w1 = wpf[1], w2 = wpf[2], w3 = wpf[3];
        const float4 t0 = row_mm(p0, w0, w1, w2, w3);
        const float4 t1 = row_mm(p1, w0, w1, w2, w3);
        const float4 t2 = row_mm(p2, w0, w1, w2, w3);
        const float4 t3 = row_mm(p3, w0, w1, w2, w3);
        float cc;
        if (mode == 0) {
            cc = 1.0f / 32.0f;
        } else {
            float d = dot4(t0,v0) + dot4(t1,v1) + dot4(t2,v2) + dot4(t3,v3);
            const float e  = __expf(d);
            const float es = sum32(e);
            cc = __fdividef(e, es);
        }
        fma4(s0, cc, t0); fma4(s1, cc, t1);
        fma4(s2, cc, t2); fma4(s3, cc, t3);
    }
    __shared__ float red[8][32][16];
    float4* rp = (float4*)&red[g][o][0];
    rp[0] = s0; rp[1] = s1; rp[2] = s2; rp[3] = s3;
    __syncthreads();
    for (int idx = tid; idx < NO * 16; idx += 256) {
        const int oo = idx >> 4;
        const int k  = idx & 15;
        float acc = red[0][oo][k];
        #pragma unroll
        for (int gg = 1; gg < 8; ++gg) acc += red[gg][oo][k];
        atomicAdd(&s_buf[(((b * NO) + oo) << 4) + k], acc);
    }
}

__global__ __launch_bounds__(256) void caps_squash_fb(
    float* __restrict__ s_buf, float* __restrict__ v_buf,
    float* __restrict__ out, const int mode)
{
    const int idx = blockIdx.x * 256 + threadIdx.x;
    if (idx >= NB * NO) return;
    float4* sp = (float4*)(s_buf + (idx << 4));
    const float4 s0 = sp[0], s1 = sp[1], s2 = sp[2], s3 = sp[3];
    const float n2 = dot4(s0,s0) + dot4(s1,s1) + dot4(s2,s2) + dot4(s3,s3);
    const float n  = sqrtf(n2 + EPSF);
    const float sc = (n2 / (1.0f + n2)) / n;
    if (mode == 2) {
        float4* op = (float4*)(out + (idx << 4));
        op[0] = make_float4(sc*s0.x, sc*s0.y, sc*s0.z, sc*s0.w);
        op[1] = make_float4(sc*s1.x, sc*s1.y, sc*s1.z, sc*s1.w);
        op[2] = make_float4(sc*s2.x, sc*s2.y, sc*s2.z, sc*s2.w);
        op[3] = make_float4(sc*s3.x, sc*s3.y, sc*s3.z, sc*s3.w);
        out[NB * NO * 16 + idx] = sqrtf(n2 * sc * sc + EPSF);
    } else {
        float4* vp = (float4*)(v_buf + (idx << 4));
        float4 a0 = {0,0,0,0}, a1 = {0,0,0,0}, a2 = {0,0,0,0}, a3 = {0,0,0,0};
        if (mode != 0) { a0 = vp[0]; a1 = vp[1]; a2 = vp[2]; a3 = vp[3]; }
        vp[0] = make_float4(fmaf(sc,s0.x,a0.x), fmaf(sc,s0.y,a0.y), fmaf(sc,s0.z,a0.z), fmaf(sc,s0.w,a0.w));
        vp[1] = make_float4(fmaf(sc,s1.x,a1.x), fmaf(sc,s1.y,a1.y), fmaf(sc,s1.z,a1.z), fmaf(sc,s1.w,a1.w));
        vp[2] = make_float4(fmaf(sc,s2.x,a2.x), fmaf(sc,s2.y,a2.y), fmaf(sc,s2.z,a2.z), fmaf(sc,s2.w,a2.w));
        vp[3] = make_float4(fmaf(sc,s3.x,a3.x), fmaf(sc,s3.y,a3.y), fmaf(sc,s3.z,a3.z), fmaf(sc,s3.w,a3.w));
        const float4 z = {0,0,0,0};
        sp[0] = z; sp[1] = z; sp[2] = z; sp[3] = z;
    }
}

extern "C" void kernel_launch(void* const* d_in, const int* in_sizes, int n_in,
                              void* d_out, int out_size, void* d_ws, size_t ws_size,
                              hipStream_t stream) {
    (void)in_sizes; (void)n_in; (void)out_size;
    const float* poses = (const float*)d_in[0];   // [B, I, 4, 4]
    // d_in[1] = input_activations — unused by the reference computation
    const float* w     = (const float*)d_in[2];   // [O, I, 4, 4]
    float* out = (float*)d_out;                   // [B,O,16] poses ++ [B,O] acts

    const size_t need = (size_t)4 * SLAB * sizeof(float);   // 256 KB
    if (ws_size >= need) {
        float* slab0   = (float*)d_ws;            // pass-0 sums
        float* slab1   = slab0 + SLAB;            // pass-1 sums
        float* slab2   = slab1 + SLAB;            // pass-2 sums
        float* v_accum = slab2 + SLAB;            // v0 (written by pass 1)
        dim3 gp(NCHUNK, NBG), blk(256);
        caps_zero<<<16, blk, 0, stream>>>((float4*)slab0);   // zero all 256 KB
        caps_pass_a<<<gp, blk, 0, stream>>>(poses, w, nullptr, v_accum, slab0, 0);
        caps_pass_a<<<gp, blk, 0, stream>>>(poses, w, slab0,  v_accum, slab1, 1);
        caps_pass_a<<<gp, blk, 0, stream>>>(poses, w, slab1,  v_accum, slab2, 2);
        caps_squash_out<<<4, blk, 0, stream>>>(slab2, out);
    } else {
        // proven v1-style path (tiny workspace)
        float* s_buf = (float*)d_ws;
        float* v_buf = s_buf + SOFF;
        (void)hipMemsetAsync(s_buf, 0, SOFF * sizeof(float), stream);
        dim3 grid(FB_CHUNKS, NB), block(256);
        for (int pass = 0; pass < 3; ++pass) {
            caps_pass_fb<<<grid, block, 0, stream>>>(poses, w, v_buf, s_buf, pass);
            caps_squash_fb<<<4, 256, 0, stream>>>(s_buf, v_buf, out, pass);
        }
    }
}

// Round 7
// 141.514 us; speedup vs baseline: 6.7316x; 6.7316x over previous
//
#include <hip/hip_runtime.h>
#include <math.h>

// DenseCaps dynamic routing, MI355X. B=32, I=4096, O=32, 4x4 poses, 3 iters.
// R16: R15 (atomic slab) catastrophic: 4.2M atomics / 64KB slab = 4096-way
// contention, 320us/pass. But its profile cleared the pass body: FETCH 8.7MB
// (L2/L3-served), VALU work ~11.7us -> the ~38us R11 pass is latency-bound,
// not traffic/VALU-bound. R13 tested occupancy confounded with a VGPR
// strangle (bounds(256,8) -> 32 VGPR, spills, 69.6us). Clean retest:
// R13 geometry (I_TILE=8, NCHUNK=512, grid 2048 = 8 blocks/CU queued) with
// bounds(256,5): VGPR cap ~85-100 >> 44 needed (R15 measured) -> no spills,
// 5 blocks/CU resident = 20 waves/CU (+25% vs R11's 16). Reduce = proven
// float4 version over 512 chunks. Everything else byte-identical to R13.

#define NB 32
#define NI 4096
#define NO 32
#define I_TILE 8
#define NCHUNK (NI / I_TILE)        // 512
#define B_TILE 8
#define NBG (NB / B_TILE)           // 4
#define SOFF (NB * NO * 16)         // 16384 floats per (chunk) partial slab
#define EPSF 1e-12f

#define W_OSTR 10                   // words per o-row: 8 data + 2 pad
#define W_ISTR (32 * W_OSTR)        // 320 words per i-slab
#define W_WORDS (I_TILE * W_ISTR)   // 2560 words = 10 KB
#define P_WORDS (B_TILE * I_TILE * 8) // 512 words = 2 KB

typedef _Float16 v2h __attribute__((ext_vector_type(2)));

#if __has_builtin(__builtin_amdgcn_fdot2)
__device__ __forceinline__ float fdot2(v2h a, v2h b, float c) {
    return __builtin_amdgcn_fdot2(a, b, c, false);
}
#else
__device__ __forceinline__ float fdot2(v2h a, v2h b, float c) {
    return fmaf((float)a.x, (float)b.x, fmaf((float)a.y, (float)b.y, c));
}
#endif

#if __has_builtin(__builtin_amdgcn_cvt_pkrtz)
__device__ __forceinline__ v2h pk2h(float a, float b) {
    return __builtin_bit_cast(v2h, __builtin_amdgcn_cvt_pkrtz(a, b));
}
#else
__device__ __forceinline__ v2h pk2h(float a, float b) {
    v2h r; r.x = (_Float16)a; r.y = (_Float16)b; return r;
}
#endif

__device__ __forceinline__ v2h bch(unsigned u) {
    return __builtin_bit_cast(v2h, u);
}

__device__ __forceinline__ float dot4(const float4 a, const float4 b) {
    return fmaf(a.x, b.x, fmaf(a.y, b.y, fmaf(a.z, b.z, a.w * b.w)));
}

__device__ __forceinline__ void fma4(float4& s, const float c, const float4 t) {
    s.x = fmaf(c, t.x, s.x);
    s.y = fmaf(c, t.y, s.y);
    s.z = fmaf(c, t.z, s.z);
    s.w = fmaf(c, t.w, s.w);
}

__device__ __forceinline__ void add4(float4& s, const float4 t) {
    s.x += t.x; s.y += t.y; s.z += t.z; s.w += t.w;
}

// x + dpp_perm(x); ctrl: 0xB1=quad_perm xor1, 0x4E=quad_perm xor2,
// 0x141=row_half_mirror (xor7), 0x140=row_mirror (xor15).
template <int CTRL>
__device__ __forceinline__ float dpp_add(float x) {
    int xi = __builtin_bit_cast(int, x);
    int yi = __builtin_amdgcn_update_dpp(0, xi, CTRL, 0xf, 0xf, false);
    return x + __builtin_bit_cast(float, yi);
}

// sum over each 32-lane half (the o-group)
__device__ __forceinline__ float sum32(float x) {
    x = dpp_add<0xB1>(x);    // xor1
    x = dpp_add<0x4E>(x);    // xor2
    x = dpp_add<0x141>(x);   // xor7 (8-group done)
    x = dpp_add<0x140>(x);   // xor15 (16-row done)
#if __has_builtin(__builtin_amdgcn_permlane16_swap)
    typedef unsigned uv2 __attribute__((ext_vector_type(2)));
    const unsigned xi = __builtin_bit_cast(unsigned, x);
    uv2 r = __builtin_amdgcn_permlane16_swap(xi, xi, false, false);
    return __builtin_bit_cast(float, r.x) + __builtin_bit_cast(float, r.y);
#else
    int t = __builtin_amdgcn_ds_swizzle(__builtin_bit_cast(int, x), 0x401F);
    return x + __builtin_bit_cast(float, t);   // xor16 within 32-lane group
#endif
}

// ---------------- pass kernel (all-LDS f16 inner loop) ----------------
// wsw word layout per (i,o): [m*4+z] = pair (W[2m][z], W[2m+1][z]).
// psw word layout per (b,i): [x*2+h] = pair (P[x][2h], P[x][2h+1]).
__global__ __launch_bounds__(256, 5) void caps_pass_h(
    const float* __restrict__ poses, const float* __restrict__ w,
    const float* __restrict__ v_buf, float* __restrict__ s_part,
    const int pass)
{
    __shared__ unsigned wsw[W_WORDS];   // 10240 B
    __shared__ unsigned psw[P_WORDS];   //  2048 B
    const int tid    = threadIdx.x;
    const int chunk  = blockIdx.x;
    const int bgroup = blockIdx.y;
    const int ibase  = chunk * I_TILE;

    // ---- stage w: f32 -> f16 pairs, coalesced ----
    #pragma unroll
    for (int r = 0; r < 2; ++r) {
        const int idx = r * 256 + tid;       // 0..511 -> (o, i, m)
        const int o_l = idx >> 4;
        const int l   = idx & 15;
        const int i_l = l >> 1;
        const int m   = l & 1;
        const float* g = w + (((size_t)o_l * NI + ibase + i_l) << 4) + (m << 3);
        const float4 A = *(const float4*)g;        // row y=2m
        const float4 B = *(const float4*)(g + 4);  // row y=2m+1
        const v2h c0 = pk2h(A.x, B.x), c1 = pk2h(A.y, B.y);
        const v2h c2 = pk2h(A.z, B.z), c3 = pk2h(A.w, B.w);
        const int base = i_l * W_ISTR + o_l * W_OSTR + (m << 2);  // even
        *(uint2*)&wsw[base]     = make_uint2(__builtin_bit_cast(unsigned, c0),
                                             __builtin_bit_cast(unsigned, c1));
        *(uint2*)&wsw[base + 2] = make_uint2(__builtin_bit_cast(unsigned, c2),
                                             __builtin_bit_cast(unsigned, c3));
    }
    // ---- stage poses: f32 -> f16 pairs, coalesced (512B run per b) ----
    {
        const int idx = tid;                 // 0..255 -> (b, i, x)
        const int b_l = idx >> 5;
        const int l   = idx & 31;
        const int i_l = l >> 2;
        const int x   = l & 3;
        const float4 row = *(const float4*)(
            poses + (((size_t)(bgroup * B_TILE + b_l) * NI + ibase + i_l) << 4)
                  + (x << 2));
        const v2h c0 = pk2h(row.x, row.y), c1 = pk2h(row.z, row.w);
        *(uint2*)&psw[((b_l * I_TILE + i_l) << 3) + (x << 1)] =
            make_uint2(__builtin_bit_cast(unsigned, c0),
                       __builtin_bit_cast(unsigned, c1));
    }

    const int o    = tid & 31;
    const int bsub = tid >> 5;
    const int b    = bgroup * B_TILE + bsub;
    const int bo   = b * NO + o;

    float4 vv0 = {0,0,0,0}, vv1 = {0,0,0,0}, vv2 = {0,0,0,0}, vv3 = {0,0,0,0};
    if (pass > 0) {
        const float4* vp = (const float4*)(v_buf + (bo << 4));
        vv0 = vp[0]; vv1 = vp[1]; vv2 = vp[2]; vv3 = vp[3];
    }

    const unsigned* wrow = &wsw[o * W_OSTR];
    const unsigned* prow = &psw[(bsub * I_TILE) << 3];

    __syncthreads();

    float4 s0 = {0,0,0,0}, s1 = {0,0,0,0}, s2 = {0,0,0,0}, s3 = {0,0,0,0};

    #pragma unroll 2
    for (int i = 0; i < I_TILE; ++i) {
        // w: 4x ds_read_b64, 10-word stride -> <=2-way (free)
        const uint2 wa = *(const uint2*)&wrow[i * W_ISTR + 0];
        const uint2 wb = *(const uint2*)&wrow[i * W_ISTR + 2];
        const uint2 wc = *(const uint2*)&wrow[i * W_ISTR + 4];
        const uint2 wd = *(const uint2*)&wrow[i * W_ISTR + 6];
        // poses: 2x ds_read_b128, broadcast (conflict-free)
        const uint4 pa = *(const uint4*)&prow[(i << 3) + 0];
        const uint4 pb = *(const uint4*)&prow[(i << 3) + 4];

        const v2h p00 = bch(pa.x), p01 = bch(pa.y);   // x0: y01, y23
        const v2h p10 = bch(pa.z), p11 = bch(pa.w);   // x1
        const v2h p20 = bch(pb.x), p21 = bch(pb.y);   // x2
        const v2h p30 = bch(pb.z), p31 = bch(pb.w);   // x3
        const v2h w00 = bch(wa.x), w01 = bch(wa.y);   // m0: z0, z1
        const v2h w02 = bch(wb.x), w03 = bch(wb.y);   // m0: z2, z3
        const v2h w10 = bch(wc.x), w11 = bch(wc.y);   // m1: z0, z1
        const v2h w12 = bch(wd.x), w13 = bch(wd.y);   // m1: z2, z3

        float4 t0, t1, t2, t3;   // votes[x][z] = sum_y P[x][y] W[y][z]
        t0.x = fdot2(p00, w00, fdot2(p01, w10, 0.0f));
        t0.y = fdot2(p00, w01, fdot2(p01, w11, 0.0f));
        t0.z = fdot2(p00, w02, fdot2(p01, w12, 0.0f));
        t0.w = fdot2(p00, w03, fdot2(p01, w13, 0.0f));
        t1.x = fdot2(p10, w00, fdot2(p11, w10, 0.0f));
        t1.y = fdot2(p10, w01, fdot2(p11, w11, 0.0f));
        t1.z = fdot2(p10, w02, fdot2(p11, w12, 0.0f));
        t1.w = fdot2(p10, w03, fdot2(p11, w13, 0.0f));
        t2.x = fdot2(p20, w00, fdot2(p21, w10, 0.0f));
        t2.y = fdot2(p20, w01, fdot2(p21, w11, 0.0f));
        t2.z = fdot2(p20, w02, fdot2(p21, w12, 0.0f));
        t2.w = fdot2(p20, w03, fdot2(p21, w13, 0.0f));
        t3.x = fdot2(p30, w00, fdot2(p31, w10, 0.0f));
        t3.y = fdot2(p30, w01, fdot2(p31, w11, 0.0f));
        t3.z = fdot2(p30, w02, fdot2(p31, w12, 0.0f));
        t3.w = fdot2(p30, w03, fdot2(p31, w13, 0.0f));

        float cc;
        if (pass == 0) {
            cc = 1.0f / 32.0f;
        } else {
            // softmax over o without max-shift: |d| bounded (~<4), exp safe.
            const float d = dot4(t0,vv0) + dot4(t1,vv1)
                          + dot4(t2,vv2) + dot4(t3,vv3);
            const float e  = __expf(d);
            const float es = sum32(e);
            cc = __fdividef(e, es);
        }
        fma4(s0, cc, t0); fma4(s1, cc, t1);
        fma4(s2, cc, t2); fma4(s3, cc, t3);
    }

    // deterministic partial store: [chunk][bo][16], fully coalesced
    float4* sp = (float4*)(s_part + ((size_t)chunk * (NB * NO) + bo) * 16);
    sp[0] = s0; sp[1] = s1; sp[2] = s2; sp[3] = s3;
}

// ---------------- reduce + squash kernel (float4 loads) ----------------
// grid 256 x 256 thr. Block owns 16 vec4 elements = 4 (b,o) pairs x 4 k4.
// thread = (grp = tid>>4 in [0,16), e = tid&15). Each thread sums 32 chunks
// as float4; 16-group LDS tree; 16 lanes finish.
__global__ __launch_bounds__(256) void caps_reduce4(
    const float* __restrict__ s_part, float* __restrict__ v_buf,
    float* __restrict__ out, const int pass)
{
    const int e   = threadIdx.x & 15;     // local vec4 id
    const int grp = threadIdx.x >> 4;     // chunk group
    const int v4g = blockIdx.x * 16 + e;  // global vec4 index = bo*4 + k4

    const float4* sp4 = (const float4*)s_part;
    float4 acc = {0, 0, 0, 0};
    #pragma unroll 8
    for (int j = 0; j < NCHUNK / 16; ++j) {
        const int c = grp + (j << 4);
        add4(acc, sp4[(size_t)c * (SOFF / 4) + v4g]);
    }

    __shared__ float4 red4[16][17];       // +1 pad
    red4[grp][e] = acc;
    __syncthreads();

    if (threadIdx.x < 16) {
        float4 a = red4[0][e];
        #pragma unroll
        for (int g = 1; g < 16; ++g) add4(a, red4[g][e]);
        // norm over the (b,o)'s 16 floats = 4 lanes (same e>>2 quad)
        float x = dot4(a, a);
        x += __shfl_xor(x, 1, 4);
        x += __shfl_xor(x, 2, 4);
        const float n2 = x;
        const float n  = sqrtf(n2 + EPSF);
        const float sc = (n2 / (1.0f + n2)) / n;
        if (pass < 2) {
            float4* vp = (float4*)v_buf + v4g;
            float4 vold = {0, 0, 0, 0};
            if (pass > 0) vold = *vp;
            *vp = make_float4(fmaf(sc, a.x, vold.x), fmaf(sc, a.y, vold.y),
                              fmaf(sc, a.z, vold.z), fmaf(sc, a.w, vold.w));
        } else {
            ((float4*)out)[v4g] =
                make_float4(sc * a.x, sc * a.y, sc * a.z, sc * a.w);
            if ((e & 3) == 0)
                out[NB * NO * 16 + (v4g >> 2)] = sqrtf(n2 * sc * sc + EPSF);
        }
    }
}

// ---------------- fallback: proven v1-style kernels (tiny ws) -------------
#define FB_CHUNKS 32
#define FB_IPB (NI / FB_CHUNKS)

__device__ __forceinline__ float4 row_mm(const float4 p, const float4 w0,
                                         const float4 w1, const float4 w2,
                                         const float4 w3) {
    float4 r;
    r.x = fmaf(p.x, w0.x, fmaf(p.y, w1.x, fmaf(p.z, w2.x, p.w * w3.x)));
    r.y = fmaf(p.x, w0.y, fmaf(p.y, w1.y, fmaf(p.z, w2.y, p.w * w3.y)));
    r.z = fmaf(p.x, w0.z, fmaf(p.y, w1.z, fmaf(p.z, w2.z, p.w * w3.z)));
    r.w = fmaf(p.x, w0.w, fmaf(p.y, w1.w, fmaf(p.z, w2.w, p.w * w3.w)));
    return r;
}

__global__ __launch_bounds__(256) void caps_pass_fb(
    const float* __restrict__ poses, const float* __restrict__ w,
    const float* __restrict__ v_buf, float* __restrict__ s_buf, const int mode)
{
    const int tid   = threadIdx.x;
    const int b     = blockIdx.y;
    const int chunk = blockIdx.x;
    const int o     = tid & 31;
    const int g     = tid >> 5;

    float4 v0 = {0,0,0,0}, v1 = {0,0,0,0}, v2 = {0,0,0,0}, v3 = {0,0,0,0};
    if (mode != 0) {
        const float4* vp = (const float4*)(v_buf + (((b * NO) + o) << 4));
        v0 = vp[0]; v1 = vp[1]; v2 = vp[2]; v3 = vp[3];
    }
    float4 s0 = {0,0,0,0}, s1 = {0,0,0,0}, s2 = {0,0,0,0}, s3 = {0,0,0,0};
    const int ibase = chunk * FB_IPB + g;
    #pragma unroll 4
    for (int it = 0; it < FB_IPB / 8; ++it) {
        const int i = ibase + (it << 3);
        const float4* ppf = (const float4*)(poses + ((((size_t)b * NI) + i) << 4));
        const float4 p0 = ppf[0], p1 = ppf[1], p2 = ppf[2], p3 = ppf[3];
        const float4* wpf = (const float4*)(w + ((((size_t)o * NI) + i) << 4));
        const float4 w0 = wpf[0], w1 = wpf[1], w2 = wpf[2], w3 = wpf[3];
        const float4 t0 = row_mm(p0, w0, w1, w2, w3);
        const float4 t1 = row_mm(p1, w0, w1, w2, w3);
        const float4 t2 = row_mm(p2, w0, w1, w2, w3);
        const float4 t3 = row_mm(p3, w0, w1, w2, w3);
        float cc;
        if (mode == 0) {
            cc = 1.0f / 32.0f;
        } else {
            float d = dot4(t0,v0) + dot4(t1,v1) + dot4(t2,v2) + dot4(t3,v3);
            const float e  = __expf(d);
            const float es = sum32(e);
            cc = __fdividef(e, es);
        }
        fma4(s0, cc, t0); fma4(s1, cc, t1);
        fma4(s2, cc, t2); fma4(s3, cc, t3);
    }
    __shared__ float red[8][32][16];
    float4* rp = (float4*)&red[g][o][0];
    rp[0] = s0; rp[1] = s1; rp[2] = s2; rp[3] = s3;
    __syncthreads();
    for (int idx = tid; idx < NO * 16; idx += 256) {
        const int oo = idx >> 4;
        const int k  = idx & 15;
        float acc = red[0][oo][k];
        #pragma unroll
        for (int gg = 1; gg < 8; ++gg) acc += red[gg][oo][k];
        atomicAdd(&s_buf[(((b * NO) + oo) << 4) + k], acc);
    }
}

__global__ __launch_bounds__(256) void caps_squash_fb(
    float* __restrict__ s_buf, float* __restrict__ v_buf,
    float* __restrict__ out, const int mode)
{
    const int idx = blockIdx.x * 256 + threadIdx.x;
    if (idx >= NB * NO) return;
    float4* sp = (float4*)(s_buf + (idx << 4));
    const float4 s0 = sp[0], s1 = sp[1], s2 = sp[2], s3 = sp[3];
    const float n2 = dot4(s0,s0) + dot4(s1,s1) + dot4(s2,s2) + dot4(s3,s3);
    const float n  = sqrtf(n2 + EPSF);
    const float sc = (n2 / (1.0f + n2)) / n;
    if (mode == 2) {
        float4* op = (float4*)(out + (idx << 4));
        op[0] = make_float4(sc*s0.x, sc*s0.y, sc*s0.z, sc*s0.w);
        op[1] = make_float4(sc*s1.x, sc*s1.y, sc*s1.z, sc*s1.w);
        op[2] = make_float4(sc*s2.x, sc*s2.y, sc*s2.z, sc*s2.w);
        op[3] = make_float4(sc*s3.x, sc*s3.y, sc*s3.z, sc*s3.w);
        out[NB * NO * 16 + idx] = sqrtf(n2 * sc * sc + EPSF);
    } else {
        float4* vp = (float4*)(v_buf + (idx << 4));
        float4 a0 = {0,0,0,0}, a1 = {0,0,0,0}, a2 = {0,0,0,0}, a3 = {0,0,0,0};
        if (mode != 0) { a0 = vp[0]; a1 = vp[1]; a2 = vp[2]; a3 = vp[3]; }
        vp[0] = make_float4(fmaf(sc,s0.x,a0.x), fmaf(sc,s0.y,a0.y), fmaf(sc,s0.z,a0.z), fmaf(sc,s0.w,a0.w));
        vp[1] = make_float4(fmaf(sc,s1.x,a1.x), fmaf(sc,s1.y,a1.y), fmaf(sc,s1.z,a1.z), fmaf(sc,s1.w,a1.w));
        vp[2] = make_float4(fmaf(sc,s2.x,a2.x), fmaf(sc,s2.y,a2.y), fmaf(sc,s2.z,a2.z), fmaf(sc,s2.w,a2.w));
        vp[3] = make_float4(fmaf(sc,s3.x,a3.x), fmaf(sc,s3.y,a3.y), fmaf(sc,s3.z,a3.z), fmaf(sc,s3.w,a3.w));
        const float4 z = {0,0,0,0};
        sp[0] = z; sp[1] = z; sp[2] = z; sp[3] = z;
    }
}

extern "C" void kernel_launch(void* const* d_in, const int* in_sizes, int n_in,
                              void* d_out, int out_size, void* d_ws, size_t ws_size,
                              hipStream_t stream) {
    (void)in_sizes; (void)n_in; (void)out_size;
    const float* poses = (const float*)d_in[0];   // [B, I, 4, 4]
    // d_in[1] = input_activations — unused by the reference computation
    const float* w     = (const float*)d_in[2];   // [O, I, 4, 4]
    float* out = (float*)d_out;                   // [B,O,16] poses ++ [B,O] acts

    const size_t need = ((size_t)NCHUNK * SOFF + SOFF) * sizeof(float);  // ~33.6 MB
    if (ws_size >= need) {
        float* s_part = (float*)d_ws;             // [NCHUNK][B*O][16]
        float* v_buf  = s_part + (size_t)NCHUNK * SOFF;
        dim3 gp(NCHUNK, NBG), blk(256), gr(256);
        for (int pass = 0; pass < 3; ++pass) {
            caps_pass_h<<<gp, blk, 0, stream>>>(poses, w, v_buf, s_part, pass);
            caps_reduce4<<<gr, blk, 0, stream>>>(s_part, v_buf, out, pass);
        }
    } else {
        // proven v1-style path (tiny workspace)
        float* s_buf = (float*)d_ws;
        float* v_buf = s_buf + SOFF;
        (void)hipMemsetAsync(s_buf, 0, SOFF * sizeof(float), stream);
        dim3 grid(FB_CHUNKS, NB), block(256);
        for (int pass = 0; pass < 3; ++pass) {
            caps_pass_fb<<<grid, block, 0, stream>>>(poses, w, v_buf, s_buf, pass);
            caps_squash_fb<<<4, 256, 0, stream>>>(s_buf, v_buf, out, pass);
        }
    }
}

// Round 8
// 128.261 us; speedup vs baseline: 7.4271x; 1.1033x over previous
//
#include <hip/hip_runtime.h>
#include <math.h>

// DenseCaps dynamic routing, MI355X. B=32, I=4096, O=32, 4x4 poses, 3 iters.
// R17: occupancy falsified both ways (R12 down +7.5, R16 up +13; R11 16w/CU
// optimal). Timestamp arithmetic (R13: 254.9 = 3x69.6 + reduces + ~30us)
// shows fills are OUTSIDE the window and launch gaps are ~5-6us each.
// R11 = 3x30us passes + 3x3 reduces + ~30us gaps; pass work models at
// <=12us. Lever left: 6 launches -> 2. R10 proved the fused dataflow
// correct (pytest passed w/ coop in eager; cross-XCD s_part reads OK under
// __threadfence) and 1024-block residency; cg::sync's ~300us/sync was the
// killer. This round: same fused kernel + hand-rolled 2-level barrier
// (32 leaves x 32 arrivals + 32-arrival root, per-epoch counters, device
// atomics, fences, s_sleep poll, spin bound). Occupancy-gated; barrier
// state zeroed per launch (ws is re-poisoned). Fallback: proven R11 path.

#define NB 32
#define NI 4096
#define NO 32
#define I_TILE 16
#define NCHUNK (NI / I_TILE)        // 256
#define B_TILE 8
#define NBG (NB / B_TILE)           // 4
#define GRID_BLKS (NCHUNK * NBG)    // 1024
#define SOFF (NB * NO * 16)         // 16384 floats
#define EPSF 1e-12f

#define W_OSTR 10                   // words per o-row: 8 data + 2 pad
#define W_ISTR (32 * W_OSTR)        // 320 words per i-slab
#define W_WORDS (I_TILE * W_ISTR)   // 5120 words = 20 KB
#define P_WORDS (B_TILE * I_TILE * 8) // 1024 words = 4 KB

// barrier geometry: 5 epochs x (32 leaves + 1 root), 128B-spaced counters
#define NLEAF 32
#define LSTR 32                     // uints between counters (128 B)
#define BAR_EPOCH ((NLEAF + 1) * LSTR)
#define BAR_WORDS (5 * BAR_EPOCH + LSTR)   // + gen word

typedef _Float16 v2h __attribute__((ext_vector_type(2)));

#if __has_builtin(__builtin_amdgcn_fdot2)
__device__ __forceinline__ float fdot2(v2h a, v2h b, float c) {
    return __builtin_amdgcn_fdot2(a, b, c, false);
}
#else
__device__ __forceinline__ float fdot2(v2h a, v2h b, float c) {
    return fmaf((float)a.x, (float)b.x, fmaf((float)a.y, (float)b.y, c));
}
#endif

#if __has_builtin(__builtin_amdgcn_cvt_pkrtz)
__device__ __forceinline__ v2h pk2h(float a, float b) {
    return __builtin_bit_cast(v2h, __builtin_amdgcn_cvt_pkrtz(a, b));
}
#else
__device__ __forceinline__ v2h pk2h(float a, float b) {
    v2h r; r.x = (_Float16)a; r.y = (_Float16)b; return r;
}
#endif

__device__ __forceinline__ v2h bch(unsigned u) {
    return __builtin_bit_cast(v2h, u);
}

__device__ __forceinline__ float dot4(const float4 a, const float4 b) {
    return fmaf(a.x, b.x, fmaf(a.y, b.y, fmaf(a.z, b.z, a.w * b.w)));
}

__device__ __forceinline__ void fma4(float4& s, const float c, const float4 t) {
    s.x = fmaf(c, t.x, s.x);
    s.y = fmaf(c, t.y, s.y);
    s.z = fmaf(c, t.z, s.z);
    s.w = fmaf(c, t.w, s.w);
}

__device__ __forceinline__ void add4(float4& s, const float4 t) {
    s.x += t.x; s.y += t.y; s.z += t.z; s.w += t.w;
}

template <int CTRL>
__device__ __forceinline__ float dpp_add(float x) {
    int xi = __builtin_bit_cast(int, x);
    int yi = __builtin_amdgcn_update_dpp(0, xi, CTRL, 0xf, 0xf, false);
    return x + __builtin_bit_cast(float, yi);
}

// sum over each 32-lane half (the o-group)
__device__ __forceinline__ float sum32(float x) {
    x = dpp_add<0xB1>(x);    // xor1
    x = dpp_add<0x4E>(x);    // xor2
    x = dpp_add<0x141>(x);   // xor7
    x = dpp_add<0x140>(x);   // xor15
#if __has_builtin(__builtin_amdgcn_permlane16_swap)
    typedef unsigned uv2 __attribute__((ext_vector_type(2)));
    const unsigned xi = __builtin_bit_cast(unsigned, x);
    uv2 r = __builtin_amdgcn_permlane16_swap(xi, xi, false, false);
    return __builtin_bit_cast(float, r.x) + __builtin_bit_cast(float, r.y);
#else
    int t = __builtin_amdgcn_ds_swizzle(__builtin_bit_cast(int, x), 0x401F);
    return x + __builtin_bit_cast(float, t);
#endif
}

// ---------------- hand-rolled grid barrier (per-epoch counters) -----------
__device__ __forceinline__ void grid_bar(unsigned* st, const int e,
                                         const int bid) {
    __syncthreads();
    if (threadIdx.x == 0) {
        __threadfence();                       // release our stores
        unsigned* base = st + (size_t)e * BAR_EPOCH;
        unsigned* leaf = base + (size_t)(bid & (NLEAF - 1)) * LSTR;
        unsigned* root = base + (size_t)NLEAF * LSTR;
        unsigned* gen  = st + (size_t)5 * BAR_EPOCH;
        if (atomicAdd(leaf, 1u) == (GRID_BLKS / NLEAF) - 1u) {
            if (atomicAdd(root, 1u) == NLEAF - 1u) {
                __threadfence();
                __hip_atomic_store(gen, (unsigned)(e + 1), __ATOMIC_RELEASE,
                                   __HIP_MEMORY_SCOPE_AGENT);
            }
        }
        long guard = 0;
        while (__hip_atomic_load(gen, __ATOMIC_ACQUIRE,
                                 __HIP_MEMORY_SCOPE_AGENT) <= (unsigned)e) {
            __builtin_amdgcn_s_sleep(2);
            if (++guard > (1L << 27)) break;   // safety valve (~bail, no hang)
        }
        __threadfence();                       // acquire others' stores
    }
    __syncthreads();
}

// ---------------- barrier-state zero kernel (24 x 256 = 6144 uints) -------
__global__ __launch_bounds__(256) void caps_bar_zero(unsigned* __restrict__ st) {
    const int i = blockIdx.x * 256 + threadIdx.x;
    if (i < BAR_WORDS) st[i] = 0u;
}

// ---------------- persistent fused kernel (R10 dataflow + fast barrier) ---
// s_part layout: [bo][chunk][16] (each block reduces rbo's 16KB run).
__global__ __launch_bounds__(256, 4) void caps_persist(
    const float* __restrict__ poses, const float* __restrict__ w,
    float* __restrict__ s_part, float* __restrict__ v_contrib,
    float* __restrict__ out, unsigned* __restrict__ bar)
{
    __shared__ unsigned wsw[W_WORDS];   // 20480 B
    __shared__ unsigned psw[P_WORDS];   //  4096 B
    __shared__ float red[16][17];       //  1088 B

    const int tid    = threadIdx.x;
    const int chunk  = blockIdx.x;
    const int bgroup = blockIdx.y;
    const int bid    = bgroup * NCHUNK + chunk;
    const int ibase  = chunk * I_TILE;

    // ---- stage w ONCE ----
    #pragma unroll
    for (int r = 0; r < 4; ++r) {
        const int idx = r * 256 + tid;       // (o, i, m)
        const int o_l = idx >> 5;
        const int l   = idx & 31;
        const int i_l = l >> 1;
        const int m   = l & 1;
        const float* g = w + (((size_t)o_l * NI + ibase + i_l) << 4) + (m << 3);
        const float4 A = *(const float4*)g;
        const float4 B = *(const float4*)(g + 4);
        const v2h c0 = pk2h(A.x, B.x), c1 = pk2h(A.y, B.y);
        const v2h c2 = pk2h(A.z, B.z), c3 = pk2h(A.w, B.w);
        const int base = i_l * W_ISTR + o_l * W_OSTR + (m << 2);
        *(uint2*)&wsw[base]     = make_uint2(__builtin_bit_cast(unsigned, c0),
                                             __builtin_bit_cast(unsigned, c1));
        *(uint2*)&wsw[base + 2] = make_uint2(__builtin_bit_cast(unsigned, c2),
                                             __builtin_bit_cast(unsigned, c3));
    }
    // ---- stage poses ONCE ----
    #pragma unroll
    for (int r = 0; r < 2; ++r) {
        const int idx = r * 256 + tid;       // (b, i, x)
        const int b_l = idx >> 6;
        const int l   = idx & 63;
        const int i_l = l >> 2;
        const int x   = l & 3;
        const float4 row = *(const float4*)(
            poses + (((size_t)(bgroup * B_TILE + b_l) * NI + ibase + i_l) << 4)
                  + (x << 2));
        const v2h c0 = pk2h(row.x, row.y), c1 = pk2h(row.z, row.w);
        *(uint2*)&psw[((b_l * I_TILE + i_l) << 3) + (x << 1)] =
            make_uint2(__builtin_bit_cast(unsigned, c0),
                       __builtin_bit_cast(unsigned, c1));
    }

    const int o    = tid & 31;
    const int bsub = tid >> 5;
    const int b    = bgroup * B_TILE + bsub;
    const int bo   = b * NO + o;
    const int rbo  = bid;                     // the (b,o) this block reduces

    const unsigned* wrow = &wsw[o * W_OSTR];
    const unsigned* prow = &psw[(bsub * I_TILE) << 3];

    float4 vv0 = {0,0,0,0}, vv1 = {0,0,0,0}, vv2 = {0,0,0,0}, vv3 = {0,0,0,0};

    __syncthreads();

    for (int pass = 0; pass < 3; ++pass) {
        float4 s0 = {0,0,0,0}, s1 = {0,0,0,0}, s2 = {0,0,0,0}, s3 = {0,0,0,0};

        #pragma unroll 2
        for (int i = 0; i < I_TILE; ++i) {
            const uint2 wa = *(const uint2*)&wrow[i * W_ISTR + 0];
            const uint2 wb = *(const uint2*)&wrow[i * W_ISTR + 2];
            const uint2 wc = *(const uint2*)&wrow[i * W_ISTR + 4];
            const uint2 wd = *(const uint2*)&wrow[i * W_ISTR + 6];
            const uint4 pa = *(const uint4*)&prow[(i << 3) + 0];
            const uint4 pb = *(const uint4*)&prow[(i << 3) + 4];

            const v2h p00 = bch(pa.x), p01 = bch(pa.y);
            const v2h p10 = bch(pa.z), p11 = bch(pa.w);
            const v2h p20 = bch(pb.x), p21 = bch(pb.y);
            const v2h p30 = bch(pb.z), p31 = bch(pb.w);
            const v2h w00 = bch(wa.x), w01 = bch(wa.y);
            const v2h w02 = bch(wb.x), w03 = bch(wb.y);
            const v2h w10 = bch(wc.x), w11 = bch(wc.y);
            const v2h w12 = bch(wd.x), w13 = bch(wd.y);

            float4 t0, t1, t2, t3;
            t0.x = fdot2(p00, w00, fdot2(p01, w10, 0.0f));
            t0.y = fdot2(p00, w01, fdot2(p01, w11, 0.0f));
            t0.z = fdot2(p00, w02, fdot2(p01, w12, 0.0f));
            t0.w = fdot2(p00, w03, fdot2(p01, w13, 0.0f));
            t1.x = fdot2(p10, w00, fdot2(p11, w10, 0.0f));
            t1.y = fdot2(p10, w01, fdot2(p11, w11, 0.0f));
            t1.z = fdot2(p10, w02, fdot2(p11, w12, 0.0f));
            t1.w = fdot2(p10, w03, fdot2(p11, w13, 0.0f));
            t2.x = fdot2(p20, w00, fdot2(p21, w10, 0.0f));
            t2.y = fdot2(p20, w01, fdot2(p21, w11, 0.0f));
            t2.z = fdot2(p20, w02, fdot2(p21, w12, 0.0f));
            t2.w = fdot2(p20, w03, fdot2(p21, w13, 0.0f));
            t3.x = fdot2(p30, w00, fdot2(p31, w10, 0.0f));
            t3.y = fdot2(p30, w01, fdot2(p31, w11, 0.0f));
            t3.z = fdot2(p30, w02, fdot2(p31, w12, 0.0f));
            t3.w = fdot2(p30, w03, fdot2(p31, w13, 0.0f));

            float cc;
            if (pass == 0) {
                cc = 1.0f / 32.0f;
            } else {
                const float d = dot4(t0,vv0) + dot4(t1,vv1)
                              + dot4(t2,vv2) + dot4(t3,vv3);
                const float e  = __expf(d);
                const float es = sum32(e);
                cc = __fdividef(e, es);
            }
            fma4(s0, cc, t0); fma4(s1, cc, t1);
            fma4(s2, cc, t2); fma4(s3, cc, t3);
        }

        // partial store: s_part[bo][chunk][16]
        float4* sp = (float4*)(s_part + (((size_t)bo * NCHUNK + chunk) << 4));
        sp[0] = s0; sp[1] = s1; sp[2] = s2; sp[3] = s3;

        grid_bar(bar, 2 * pass, bid);

        // ---- reduce rbo: block reads its own contiguous 16KB run ----
        {
            const int k   = tid & 15;
            const int grp = tid >> 4;
            const float* base = s_part + ((size_t)rbo << 12);  // rbo*256*16
            float acc = 0.0f;
            #pragma unroll
            for (int j = 0; j < 16; ++j)
                acc += base[((grp + (j << 4)) << 4) + k];
            red[grp][k] = acc;
        }
        __syncthreads();
        if (tid < 16) {
            float a = red[0][tid];
            #pragma unroll
            for (int g2 = 1; g2 < 16; ++g2) a += red[g2][tid];
            float x = a * a;
            #pragma unroll
            for (int msk = 8; msk >= 1; msk >>= 1)
                x += __shfl_xor(x, msk, 16);
            const float n2 = x;
            const float n  = sqrtf(n2 + EPSF);
            const float sc = (n2 / (1.0f + n2)) / n;
            if (pass < 2) {
                v_contrib[(rbo << 4) + tid] = sc * a;
            } else {
                out[(rbo << 4) + tid] = sc * a;
                if (tid == 0)
                    out[NB * NO * 16 + rbo] = sqrtf(n2 * sc * sc + EPSF);
            }
        }
        if (pass == 2) break;

        grid_bar(bar, 2 * pass + 1, bid);

        const float4* vp = (const float4*)(v_contrib + (bo << 4));
        add4(vv0, vp[0]); add4(vv1, vp[1]);
        add4(vv2, vp[2]); add4(vv3, vp[3]);
    }
}

// ---------------- fallback A: proven R11 two-kernel path ------------------
__global__ __launch_bounds__(256, 4) void caps_pass_h(
    const float* __restrict__ poses, const float* __restrict__ w,
    const float* __restrict__ v_buf, float* __restrict__ s_part,
    const int pass)
{
    __shared__ unsigned wsw[W_WORDS];
    __shared__ unsigned psw[P_WORDS];
    const int tid    = threadIdx.x;
    const int chunk  = blockIdx.x;
    const int bgroup = blockIdx.y;
    const int ibase  = chunk * I_TILE;

    #pragma unroll
    for (int r = 0; r < 4; ++r) {
        const int idx = r * 256 + tid;
        const int o_l = idx >> 5;
        const int l   = idx & 31;
        const int i_l = l >> 1;
        const int m   = l & 1;
        const float* g = w + (((size_t)o_l * NI + ibase + i_l) << 4) + (m << 3);
        const float4 A = *(const float4*)g;
        const float4 B = *(const float4*)(g + 4);
        const v2h c0 = pk2h(A.x, B.x), c1 = pk2h(A.y, B.y);
        const v2h c2 = pk2h(A.z, B.z), c3 = pk2h(A.w, B.w);
        const int base = i_l * W_ISTR + o_l * W_OSTR + (m << 2);
        *(uint2*)&wsw[base]     = make_uint2(__builtin_bit_cast(unsigned, c0),
                                             __builtin_bit_cast(unsigned, c1));
        *(uint2*)&wsw[base + 2] = make_uint2(__builtin_bit_cast(unsigned, c2),
                                             __builtin_bit_cast(unsigned, c3));
    }
    #pragma unroll
    for (int r = 0; r < 2; ++r) {
        const int idx = r * 256 + tid;
        const int b_l = idx >> 6;
        const int l   = idx & 63;
        const int i_l = l >> 2;
        const int x   = l & 3;
        const float4 row = *(const float4*)(
            poses + (((size_t)(bgroup * B_TILE + b_l) * NI + ibase + i_l) << 4)
                  + (x << 2));
        const v2h c0 = pk2h(row.x, row.y), c1 = pk2h(row.z, row.w);
        *(uint2*)&psw[((b_l * I_TILE + i_l) << 3) + (x << 1)] =
            make_uint2(__builtin_bit_cast(unsigned, c0),
                       __builtin_bit_cast(unsigned, c1));
    }

    const int o    = tid & 31;
    const int bsub = tid >> 5;
    const int b    = bgroup * B_TILE + bsub;
    const int bo   = b * NO + o;

    float4 vv0 = {0,0,0,0}, vv1 = {0,0,0,0}, vv2 = {0,0,0,0}, vv3 = {0,0,0,0};
    if (pass > 0) {
        const float4* vp = (const float4*)(v_buf + (bo << 4));
        vv0 = vp[0]; vv1 = vp[1]; vv2 = vp[2]; vv3 = vp[3];
    }

    const unsigned* wrow = &wsw[o * W_OSTR];
    const unsigned* prow = &psw[(bsub * I_TILE) << 3];

    __syncthreads();

    float4 s0 = {0,0,0,0}, s1 = {0,0,0,0}, s2 = {0,0,0,0}, s3 = {0,0,0,0};

    #pragma unroll 2
    for (int i = 0; i < I_TILE; ++i) {
        const uint2 wa = *(const uint2*)&wrow[i * W_ISTR + 0];
        const uint2 wb = *(const uint2*)&wrow[i * W_ISTR + 2];
        const uint2 wc = *(const uint2*)&wrow[i * W_ISTR + 4];
        const uint2 wd = *(const uint2*)&wrow[i * W_ISTR + 6];
        const uint4 pa = *(const uint4*)&prow[(i << 3) + 0];
        const uint4 pb = *(const uint4*)&prow[(i << 3) + 4];

        const v2h p00 = bch(pa.x), p01 = bch(pa.y);
        const v2h p10 = bch(pa.z), p11 = bch(pa.w);
        const v2h p20 = bch(pb.x), p21 = bch(pb.y);
        const v2h p30 = bch(pb.z), p31 = bch(pb.w);
        const v2h w00 = bch(wa.x), w01 = bch(wa.y);
        const v2h w02 = bch(wb.x), w03 = bch(wb.y);
        const v2h w10 = bch(wc.x), w11 = bch(wc.y);
        const v2h w12 = bch(wd.x), w13 = bch(wd.y);

        float4 t0, t1, t2, t3;
        t0.x = fdot2(p00, w00, fdot2(p01, w10, 0.0f));
        t0.y = fdot2(p00, w01, fdot2(p01, w11, 0.0f));
        t0.z = fdot2(p00, w02, fdot2(p01, w12, 0.0f));
        t0.w = fdot2(p00, w03, fdot2(p01, w13, 0.0f));
        t1.x = fdot2(p10, w00, fdot2(p11, w10, 0.0f));
        t1.y = fdot2(p10, w01, fdot2(p11, w11, 0.0f));
        t1.z = fdot2(p10, w02, fdot2(p11, w12, 0.0f));
        t1.w = fdot2(p10, w03, fdot2(p11, w13, 0.0f));
        t2.x = fdot2(p20, w00, fdot2(p21, w10, 0.0f));
        t2.y = fdot2(p20, w01, fdot2(p21, w11, 0.0f));
        t2.z = fdot2(p20, w02, fdot2(p21, w12, 0.0f));
        t2.w = fdot2(p20, w03, fdot2(p21, w13, 0.0f));
        t3.x = fdot2(p30, w00, fdot2(p31, w10, 0.0f));
        t3.y = fdot2(p30, w01, fdot2(p31, w11, 0.0f));
        t3.z = fdot2(p30, w02, fdot2(p31, w12, 0.0f));
        t3.w = fdot2(p30, w03, fdot2(p31, w13, 0.0f));

        float cc;
        if (pass == 0) {
            cc = 1.0f / 32.0f;
        } else {
            const float d = dot4(t0,vv0) + dot4(t1,vv1)
                          + dot4(t2,vv2) + dot4(t3,vv3);
            const float e  = __expf(d);
            const float es = sum32(e);
            cc = __fdividef(e, es);
        }
        fma4(s0, cc, t0); fma4(s1, cc, t1);
        fma4(s2, cc, t2); fma4(s3, cc, t3);
    }

    float4* sp = (float4*)(s_part + ((size_t)chunk * (NB * NO) + bo) * 16);
    sp[0] = s0; sp[1] = s1; sp[2] = s2; sp[3] = s3;
}

__global__ __launch_bounds__(256) void caps_reduce4(
    const float* __restrict__ s_part, float* __restrict__ v_buf,
    float* __restrict__ out, const int pass)
{
    const int e   = threadIdx.x & 15;
    const int grp = threadIdx.x >> 4;
    const int v4g = blockIdx.x * 16 + e;

    const float4* sp4 = (const float4*)s_part;
    float4 acc = {0, 0, 0, 0};
    #pragma unroll
    for (int j = 0; j < NCHUNK / 16; ++j) {
        const int c = grp + (j << 4);
        add4(acc, sp4[(size_t)c * (SOFF / 4) + v4g]);
    }

    __shared__ float4 red4[16][17];
    red4[grp][e] = acc;
    __syncthreads();

    if (threadIdx.x < 16) {
        float4 a = red4[0][e];
        #pragma unroll
        for (int g = 1; g < 16; ++g) add4(a, red4[g][e]);
        float x = dot4(a, a);
        x += __shfl_xor(x, 1, 4);
        x += __shfl_xor(x, 2, 4);
        const float n2 = x;
        const float n  = sqrtf(n2 + EPSF);
        const float sc = (n2 / (1.0f + n2)) / n;
        if (pass < 2) {
            float4* vp = (float4*)v_buf + v4g;
            float4 vold = {0, 0, 0, 0};
            if (pass > 0) vold = *vp;
            *vp = make_float4(fmaf(sc, a.x, vold.x), fmaf(sc, a.y, vold.y),
                              fmaf(sc, a.z, vold.z), fmaf(sc, a.w, vold.w));
        } else {
            ((float4*)out)[v4g] =
                make_float4(sc * a.x, sc * a.y, sc * a.z, sc * a.w);
            if ((e & 3) == 0)
                out[NB * NO * 16 + (v4g >> 2)] = sqrtf(n2 * sc * sc + EPSF);
        }
    }
}

// ---------------- fallback B: proven v1-style kernels (tiny ws) -----------
#define FB_CHUNKS 32
#define FB_IPB (NI / FB_CHUNKS)

__device__ __forceinline__ float4 row_mm(const float4 p, const float4 w0,
                                         const float4 w1, const float4 w2,
                                         const float4 w3) {
    float4 r;
    r.x = fmaf(p.x, w0.x, fmaf(p.y, w1.x, fmaf(p.z, w2.x, p.w * w3.x)));
    r.y = fmaf(p.x, w0.y, fmaf(p.y, w1.y, fmaf(p.z, w2.y, p.w * w3.y)));
    r.z = fmaf(p.x, w0.z, fmaf(p.y, w1.z, fmaf(p.z, w2.z, p.w * w3.z)));
    r.w = fmaf(p.x, w0.w, fmaf(p.y, w1.w, fmaf(p.z, w2.w, p.w * w3.w)));
    return r;
}

__global__ __launch_bounds__(256) void caps_pass_fb(
    const float* __restrict__ poses, const float* __restrict__ w,
    const float* __restrict__ v_buf, float* __restrict__ s_buf, const int mode)
{
    const int tid   = threadIdx.x;
    const int b     = blockIdx.y;
    const int chunk = blockIdx.x;
    const int o     = tid & 31;
    const int g     = tid >> 5;

    float4 v0 = {0,0,0,0}, v1 = {0,0,0,0}, v2 = {0,0,0,0}, v3 = {0,0,0,0};
    if (mode != 0) {
        const float4* vp = (const float4*)(v_buf + (((b * NO) + o) << 4));
        v0 = vp[0]; v1 = vp[1]; v2 = vp[2]; v3 = vp[3];
    }
    float4 s0 = {0,0,0,0}, s1 = {0,0,0,0}, s2 = {0,0,0,0}, s3 = {0,0,0,0};
    const int ibase = chunk * FB_IPB + g;
    #pragma unroll 4
    for (int it = 0; it < FB_IPB / 8; ++it) {
        const int i = ibase + (it << 3);
        const float4* ppf = (const float4*)(poses + ((((size_t)b * NI) + i) << 4));
        const float4 p0 = ppf[0], p1 = ppf[1], p2 = ppf[2], p3 = ppf[3];
        const float4* wpf = (const float4*)(w + ((((size_t)o * NI) + i) << 4));
        const float4 w0 = wpf[0], w1 = wpf[1], w2 = wpf[2], w3 = wpf[3];
        const float4 t0 = row_mm(p0, w0, w1, w2, w3);
        const float4 t1 = row_mm(p1, w0, w1, w2, w3);
        const float4 t2 = row_mm(p2, w0, w1, w2, w3);
        const float4 t3 = row_mm(p3, w0, w1, w2, w3);
        float cc;
        if (mode == 0) {
            cc = 1.0f / 32.0f;
        } else {
            float d = dot4(t0,v0) + dot4(t1,v1) + dot4(t2,v2) + dot4(t3,v3);
            const float e  = __expf(d);
            const float es = sum32(e);
            cc = __fdividef(e, es);
        }
        fma4(s0, cc, t0); fma4(s1, cc, t1);
        fma4(s2, cc, t2); fma4(s3, cc, t3);
    }
    __shared__ float red[8][32][16];
    float4* rp = (float4*)&red[g][o][0];
    rp[0] = s0; rp[1] = s1; rp[2] = s2; rp[3] = s3;
    __syncthreads();
    for (int idx = tid; idx < NO * 16; idx += 256) {
        const int oo = idx >> 4;
        const int k  = idx & 15;
        float acc = red[0][oo][k];
        #pragma unroll
        for (int gg = 1; gg < 8; ++gg) acc += red[gg][oo][k];
        atomicAdd(&s_buf[(((b * NO) + oo) << 4) + k], acc);
    }
}

__global__ __launch_bounds__(256) void caps_squash_fb(
    float* __restrict__ s_buf, float* __restrict__ v_buf,
    float* __restrict__ out, const int mode)
{
    const int idx = blockIdx.x * 256 + threadIdx.x;
    if (idx >= NB * NO) return;
    float4* sp = (float4*)(s_buf + (idx << 4));
    const float4 s0 = sp[0], s1 = sp[1], s2 = sp[2], s3 = sp[3];
    const float n2 = dot4(s0,s0) + dot4(s1,s1) + dot4(s2,s2) + dot4(s3,s3);
    const float n  = sqrtf(n2 + EPSF);
    const float sc = (n2 / (1.0f + n2)) / n;
    if (mode == 2) {
        float4* op = (float4*)(out + (idx << 4));
        op[0] = make_float4(sc*s0.x, sc*s0.y, sc*s0.z, sc*s0.w);
        op[1] = make_float4(sc*s1.x, sc*s1.y, sc*s1.z, sc*s1.w);
        op[2] = make_float4(sc*s2.x, sc*s2.y, sc*s2.z, sc*s2.w);
        op[3] = make_float4(sc*s3.x, sc*s3.y, sc*s3.z, sc*s3.w);
        out[NB * NO * 16 + idx] = sqrtf(n2 * sc * sc + EPSF);
    } else {
        float4* vp = (float4*)(v_buf + (idx << 4));
        float4 a0 = {0,0,0,0}, a1 = {0,0,0,0}, a2 = {0,0,0,0}, a3 = {0,0,0,0};
        if (mode != 0) { a0 = vp[0]; a1 = vp[1]; a2 = vp[2]; a3 = vp[3]; }
        vp[0] = make_float4(fmaf(sc,s0.x,a0.x), fmaf(sc,s0.y,a0.y), fmaf(sc,s0.z,a0.z), fmaf(sc,s0.w,a0.w));
        vp[1] = make_float4(fmaf(sc,s1.x,a1.x), fmaf(sc,s1.y,a1.y), fmaf(sc,s1.z,a1.z), fmaf(sc,s1.w,a1.w));
        vp[2] = make_float4(fmaf(sc,s2.x,a2.x), fmaf(sc,s2.y,a2.y), fmaf(sc,s2.z,a2.z), fmaf(sc,s2.w,a2.w));
        vp[3] = make_float4(fmaf(sc,s3.x,a3.x), fmaf(sc,s3.y,a3.y), fmaf(sc,s3.z,a3.z), fmaf(sc,s3.w,a3.w));
        const float4 z = {0,0,0,0};
        sp[0] = z; sp[1] = z; sp[2] = z; sp[3] = z;
    }
}

extern "C" void kernel_launch(void* const* d_in, const int* in_sizes, int n_in,
                              void* d_out, int out_size, void* d_ws, size_t ws_size,
                              hipStream_t stream) {
    (void)in_sizes; (void)n_in; (void)out_size;
    const float* poses = (const float*)d_in[0];   // [B, I, 4, 4]
    const float* w     = (const float*)d_in[2];   // [O, I, 4, 4]
    float* out = (float*)d_out;                   // [B,O,16] poses ++ [B,O] acts

    const size_t n_spart = (size_t)NCHUNK * SOFF;                 // 16.8 MB
    const size_t need = (n_spart + SOFF) * 4 + BAR_WORDS * 4 + 256;
    if (ws_size >= need) {
        float*    s_part = (float*)d_ws;
        float*    v_buf  = s_part + n_spart;
        unsigned* bar    = (unsigned*)(v_buf + SOFF);

        // occupancy gate for the persistent path (cached; baked at capture)
        static int occ = -1;
        if (occ < 0) {
            int t = 0;
            hipError_t e = hipOccupancyMaxActiveBlocksPerMultiprocessor(
                &t, caps_persist, 256, 0);
            occ = (e == hipSuccess) ? t : 0;
            (void)hipGetLastError();
        }
        if (occ >= 4) {
            dim3 gp(NCHUNK, NBG), blk(256);
            caps_bar_zero<<<(BAR_WORDS + 255) / 256, blk, 0, stream>>>(bar);
            caps_persist<<<gp, blk, 0, stream>>>(poses, w, s_part, v_buf,
                                                 out, bar);
        } else {
            dim3 gp(NCHUNK, NBG), blk(256), gr(256);
            for (int pass = 0; pass < 3; ++pass) {
                caps_pass_h<<<gp, blk, 0, stream>>>(poses, w, v_buf, s_part, pass);
                caps_reduce4<<<gr, blk, 0, stream>>>(s_part, v_buf, out, pass);
            }
        }
    } else {
        float* s_buf = (float*)d_ws;
        float* v_buf = s_buf + SOFF;
        (void)hipMemsetAsync(s_buf, 0, SOFF * sizeof(float), stream);
        dim3 grid(FB_CHUNKS, NB), block(256);
        for (int pass = 0; pass < 3; ++pass) {
            caps_pass_fb<<<grid, block, 0, stream>>>(poses, w, v_buf, s_buf, pass);
            caps_squash_fb<<<4, 256, 0, stream>>>(s_buf, v_buf, out, pass);
        }
    }
}